// Round 3
// baseline (290.991 us; speedup 1.0000x reference)
//
#include <hip/hip_runtime.h>
#include <stdint.h>
#include <stddef.h>

// Problem constants (match reference setup_inputs)
#define B_    16
#define P_    16
#define S_    512
#define D_    256
#define DFF_  1024
#define VOCAB_ 5000
#define T_    256
#define ROWS_ 256        // B*P
#define EPS_  1e-6f

#define PARTITIONABLE 1  // jax_threefry_partitionable=True (verified in R1)

// ---------------- threefry2x32 (JAX reference cipher) ----------------
__host__ __device__ __forceinline__ uint32_t rotl32_(uint32_t x, int d) {
  return (x << d) | (x >> (32 - d));
}

__host__ __device__ __forceinline__ void threefry2x32_(uint32_t k0, uint32_t k1,
                                                       uint32_t x0, uint32_t x1,
                                                       uint32_t& o0, uint32_t& o1) {
  uint32_t ks2 = k0 ^ k1 ^ 0x1BD11BDAu;
  x0 += k0; x1 += k1;
  x0 += x1; x1 = rotl32_(x1, 13); x1 ^= x0;
  x0 += x1; x1 = rotl32_(x1, 15); x1 ^= x0;
  x0 += x1; x1 = rotl32_(x1, 26); x1 ^= x0;
  x0 += x1; x1 = rotl32_(x1,  6); x1 ^= x0;
  x0 += k1; x1 += ks2 + 1u;
  x0 += x1; x1 = rotl32_(x1, 17); x1 ^= x0;
  x0 += x1; x1 = rotl32_(x1, 29); x1 ^= x0;
  x0 += x1; x1 = rotl32_(x1, 16); x1 ^= x0;
  x0 += x1; x1 = rotl32_(x1, 24); x1 ^= x0;
  x0 += ks2; x1 += k0 + 2u;
  x0 += x1; x1 = rotl32_(x1, 13); x1 ^= x0;
  x0 += x1; x1 = rotl32_(x1, 15); x1 ^= x0;
  x0 += x1; x1 = rotl32_(x1, 26); x1 ^= x0;
  x0 += x1; x1 = rotl32_(x1,  6); x1 ^= x0;
  x0 += k0; x1 += k1 + 3u;
  x0 += x1; x1 = rotl32_(x1, 17); x1 ^= x0;
  x0 += x1; x1 = rotl32_(x1, 29); x1 ^= x0;
  x0 += x1; x1 = rotl32_(x1, 16); x1 ^= x0;
  x0 += x1; x1 = rotl32_(x1, 24); x1 ^= x0;
  x0 += k1; x1 += ks2 + 4u;
  x0 += x1; x1 = rotl32_(x1, 13); x1 ^= x0;
  x0 += x1; x1 = rotl32_(x1, 15); x1 ^= x0;
  x0 += x1; x1 = rotl32_(x1, 26); x1 ^= x0;
  x0 += x1; x1 = rotl32_(x1,  6); x1 ^= x0;
  x0 += ks2; x1 += k0 + 5u;
  o0 = x0; o1 = x1;
}

__device__ __forceinline__ uint32_t jax_bits(uint32_t k0, uint32_t k1,
                                             uint32_t i, uint32_t half) {
#if PARTITIONABLE
  uint32_t o0, o1;
  threefry2x32_(k0, k1, 0u, i, o0, o1);
  return o0 ^ o1;
#else
  uint32_t o0, o1;
  uint32_t lo = (i < half) ? i : (i - half);
  threefry2x32_(k0, k1, lo, lo + half, o0, o1);
  return (i < half) ? o0 : o1;
#endif
}

__device__ __forceinline__ float bits_to_u01(uint32_t b) {
  return __uint_as_float((b >> 9) | 0x3F800000u) - 1.0f;
}

// XLA f32 ErfInv (Giles polynomial)
__device__ __forceinline__ float erfinv32(float x) {
  float w = -log1pf(-x * x);
  float p;
  if (w < 5.0f) {
    w -= 2.5f;
    p = 2.81022636e-08f;
    p = fmaf(p, w, 3.43273939e-07f);
    p = fmaf(p, w, -3.5233877e-06f);
    p = fmaf(p, w, -4.39150654e-06f);
    p = fmaf(p, w, 0.00021858087f);
    p = fmaf(p, w, -0.00125372503f);
    p = fmaf(p, w, -0.00417768164f);
    p = fmaf(p, w, 0.246640727f);
    p = fmaf(p, w, 1.50140941f);
  } else {
    w = sqrtf(w) - 3.0f;
    p = -0.000200214257f;
    p = fmaf(p, w, 0.000100950558f);
    p = fmaf(p, w, 0.00134934322f);
    p = fmaf(p, w, -0.00367342844f);
    p = fmaf(p, w, 0.00573950773f);
    p = fmaf(p, w, -0.0076224613f);
    p = fmaf(p, w, 0.00943887047f);
    p = fmaf(p, w, 1.00167406f);
    p = fmaf(p, w, 2.83297682f);
  }
  return p * x;
}

__device__ __forceinline__ float jax_normal(uint32_t k0, uint32_t k1,
                                            uint32_t i, uint32_t half) {
  float u01 = bits_to_u01(jax_bits(k0, k1, i, half));
  const float lo = -0.99999994f;
  float u = __fadd_rn(__fmul_rn(u01, 2.0f), lo);
  u = fmaxf(lo, u);
  return 1.41421356f * erfinv32(u);
}

__device__ __forceinline__ float jax_gumbel(uint32_t k0, uint32_t k1,
                                            uint32_t i, uint32_t half) {
  float u01 = bits_to_u01(jax_bits(k0, k1, i, half));
  const float tiny = 1.17549435e-38f;
  float u = __fadd_rn(__fmul_rn(u01, 1.0f), tiny);
  u = fmaxf(tiny, u);
  return -logf(-logf(u));
}

// ---------------- 1024-thread block reductions (wave shfl + 16-slot LDS) ----
__device__ __forceinline__ float blk_sum(float v, float* red, int tid) {
  #pragma unroll
  for (int off = 32; off > 0; off >>= 1) v += __shfl_xor(v, off, 64);
  if ((tid & 63) == 0) red[tid >> 6] = v;
  __syncthreads();
  if (tid == 0) {
    float s = 0.f;
    #pragma unroll
    for (int i = 0; i < 16; i++) s += red[i];
    red[16] = s;
  }
  __syncthreads();
  float r = red[16];
  __syncthreads();
  return r;
}
__device__ __forceinline__ float blk_max(float v, float* red, int tid) {
  #pragma unroll
  for (int off = 32; off > 0; off >>= 1) v = fmaxf(v, __shfl_xor(v, off, 64));
  if ((tid & 63) == 0) red[tid >> 6] = v;
  __syncthreads();
  if (tid == 0) {
    float s = -INFINITY;
    #pragma unroll
    for (int i = 0; i < 16; i++) s = fmaxf(s, red[i]);
    red[16] = s;
  }
  __syncthreads();
  float r = red[16];
  __syncthreads();
  return r;
}

// ---------------- fused per-row kernel: qkv+noise+attn+wo+LN1+FFN+LN2 -------
// grid = 256 rows, block = 1024 threads (16 waves/CU for latency hiding)
__global__ __launch_bounds__(1024) void fused_row_kernel(
    const float* __restrict__ x,
    const float* __restrict__ Kin, const float* __restrict__ Vin,
    const float* __restrict__ wq, const float* __restrict__ bq,
    const float* __restrict__ wk, const float* __restrict__ bk,
    const float* __restrict__ wv, const float* __restrict__ bv,
    const float* __restrict__ wo, const float* __restrict__ bo,
    const float* __restrict__ w1, const float* __restrict__ b1,
    const float* __restrict__ w2, const float* __restrict__ b2,
    const float* __restrict__ ln1g, const float* __restrict__ ln1b,
    const float* __restrict__ ln2g, const float* __restrict__ ln2b,
    const float* __restrict__ sigmas,
    float* __restrict__ kws, float* __restrict__ vws,
    float* __restrict__ attn_out, float* __restrict__ noiseq_out,
    float* __restrict__ noisez_out, float* __restrict__ r_out,
    uint32_t kq0, uint32_t kq1, uint32_t kk0, uint32_t kk1,
    uint32_t kv0, uint32_t kv1, uint32_t kz0, uint32_t kz1) {
  __shared__ float xs[D_], qs[D_], ksh[D_], vsh[D_], z0s[D_], os[D_];
  __shared__ float att[T_ + 4];
  __shared__ float hs[DFF_];
  __shared__ float sc3[3][4][D_];   // split-K partials
  __shared__ float red[32];
  const int row = blockIdx.x, t = threadIdx.x;
  const int col = t & 255, ec = t >> 8;      // ec in [0,4)

  if (t < D_) xs[t] = x[row * D_ + t];
  __syncthreads();

  // ---- QKV: each quarter-thread-group accumulates a 64-long K-slice ----
  {
    float aq = 0.f, ak = 0.f, av = 0.f;
    const int e0 = ec * 64;
    #pragma unroll 8
    for (int e = e0; e < e0 + 64; e++) {
      float xe = xs[e];
      aq = fmaf(xe, wq[e * D_ + col], aq);
      ak = fmaf(xe, wk[e * D_ + col], ak);
      av = fmaf(xe, wv[e * D_ + col], av);
    }
    sc3[0][ec][col] = aq; sc3[1][ec][col] = ak; sc3[2][ec][col] = av;
  }
  __syncthreads();
  if (t < D_) {
    float qf = bq[t] + sc3[0][0][t] + sc3[0][1][t] + sc3[0][2][t] + sc3[0][3][t];
    float kf = bk[t] + sc3[1][0][t] + sc3[1][1][t] + sc3[1][2][t] + sc3[1][3][t];
    float vf = bv[t] + sc3[2][0][t] + sc3[2][1][t] + sc3[2][2][t] + sc3[2][3][t];
    uint32_t i = (uint32_t)row * D_ + t;
    float qn = qf + sigmas[0] * jax_normal(kq0, kq1, i, 32768u);
    float kn = kf + sigmas[1] * jax_normal(kk0, kk1, i, 32768u);
    float vn = vf + sigmas[2] * jax_normal(kv0, kv1, i, 32768u);
    qs[t] = qn; ksh[t] = kn; vsh[t] = vn;
    kws[i] = kn; vws[i] = vn;
    noiseq_out[i] = qn - qf;
  }
  __syncthreads();

  // ---- logits: 16 waves, 4 s-values per wave per round, float4 dot ----
  {
    const int wid = t >> 6, lane = t & 63;
    float4 myq = ((const float4*)qs)[lane];
    for (int s0 = wid * 4; s0 <= T_; s0 += 64) {
      #pragma unroll
      for (int j = 0; j < 4; j++) {
        int s = s0 + j;
        if (s <= T_) {
          const float* Krow = (s == T_) ? ksh
                                        : (Kin + ((size_t)row * S_ + s) * D_);
          float4 k4 = ((const float4*)Krow)[lane];
          float rr = myq.x * k4.x + myq.y * k4.y + myq.z * k4.z + myq.w * k4.w;
          #pragma unroll
          for (int off = 32; off > 0; off >>= 1) rr += __shfl_xor(rr, off, 64);
          if (lane == 0) att[s] = rr * 0.0625f;   // / sqrt(256)
        }
      }
    }
  }
  __syncthreads();

  // ---- softmax over 257 logits ----
  {
    float v = (t <= T_) ? att[t] : -INFINITY;
    float mx = blk_max(v, red, t);
    float e = (t <= T_) ? expf(att[t] - mx) : 0.f;
    float sum = blk_sum(e, red, t);
    if (t <= T_) {
      float a = e / sum;
      att[t] = a;
      attn_out[(size_t)row * (T_ + 1) + t] = a;
    }
  }
  __syncthreads();

  // ---- z0 = attn @ Vw (split s-range across ec) ----
  {
    float acc = 0.f;
    const int s0 = ec * 64;
    #pragma unroll 8
    for (int s = s0; s < s0 + 64; s++)
      acc = fmaf(att[s], Vin[((size_t)row * S_ + s) * D_ + col], acc);
    if (ec == 3) acc = fmaf(att[T_], vsh[col], acc);
    sc3[0][ec][col] = acc;
  }
  __syncthreads();
  if (t < D_) z0s[t] = sc3[0][0][t] + sc3[0][1][t] + sc3[0][2][t] + sc3[0][3][t];
  __syncthreads();

  // ---- z = z0 @ wo + bo + noise; y = z + x; LN1 ----
  {
    float acc = 0.f;
    const int e0 = ec * 64;
    #pragma unroll 8
    for (int e = e0; e < e0 + 64; e++)
      acc = fmaf(z0s[e], wo[e * D_ + col], acc);
    sc3[0][ec][col] = acc;
  }
  __syncthreads();
  if (t < D_) {
    float zp = bo[t] + sc3[0][0][t] + sc3[0][1][t] + sc3[0][2][t] + sc3[0][3][t];
    uint32_t i = (uint32_t)row * D_ + t;
    float zn = zp + sigmas[3] * jax_normal(kz0, kz1, i, 32768u);
    noisez_out[i] = zn - zp;
    z0s[t] = zn + xs[t];     // reuse z0s as y
  }
  __syncthreads();
  {
    float y = (t < D_) ? z0s[t] : 0.f;
    float mu = blk_sum(y, red, t) * (1.0f / 256.0f);
    float dv = (t < D_) ? (z0s[t] - mu) : 0.f;
    float var = blk_sum(dv * dv, red, t) * (1.0f / 256.0f);
    if (t < D_) os[t] = dv * rsqrtf(var + EPS_) * ln1g[t] + ln1b[t];
  }
  __syncthreads();

  // ---- FFN layer 1: all 1024 threads, one DFF output each ----
  {
    float acc = b1[t];
    #pragma unroll 8
    for (int e = 0; e < D_; e++) acc = fmaf(os[e], w1[(size_t)e * DFF_ + t], acc);
    hs[t] = fmaxf(acc, 0.f);
  }
  __syncthreads();

  // ---- FFN layer 2: split 1024-long K across ec ----
  {
    float acc = 0.f;
    const int e0 = ec * 256;
    #pragma unroll 8
    for (int e = e0; e < e0 + 256; e++)
      acc = fmaf(hs[e], w2[(size_t)e * D_ + col], acc);
    sc3[0][ec][col] = acc;
  }
  __syncthreads();
  if (t < D_) {
    float f = b2[t] + sc3[0][0][t] + sc3[0][1][t] + sc3[0][2][t] + sc3[0][3][t];
    z0s[t] = f + os[t];
  }
  __syncthreads();
  {
    float y = (t < D_) ? z0s[t] : 0.f;
    float mu = blk_sum(y, red, t) * (1.0f / 256.0f);
    float dv = (t < D_) ? (z0s[t] - mu) : 0.f;
    float var = blk_sum(dv * dv, red, t) * (1.0f / 256.0f);
    if (t < D_)
      r_out[(size_t)row * D_ + t] = dv * rsqrtf(var + EPS_) * ln2g[t] + ln2b[t];
  }
}

// ---------------- preds = r @ w_out (256x5000x256) ----------------
__global__ __launch_bounds__(256) void preds_kernel(
    const float* __restrict__ r, const float* __restrict__ w_out,
    float* __restrict__ preds) {
  int tid = threadIdx.x;
  int col = blockIdx.x * 250 + tid;
  int rb = blockIdx.y * 16;
  if (tid >= 250) return;
  float acc[16];
  #pragma unroll
  for (int m = 0; m < 16; m++) acc[m] = 0.f;
  #pragma unroll 4
  for (int e = 0; e < D_; e++) {
    float wv = w_out[(size_t)e * VOCAB_ + col];
    #pragma unroll
    for (int m = 0; m < 16; m++)
      acc[m] = fmaf(r[(size_t)(rb + m) * D_ + e], wv, acc[m]);
  }
  #pragma unroll
  for (int m = 0; m < 16; m++)
    preds[(size_t)(rb + m) * VOCAB_ + col] = acc[m];
}

// ---------------- softmax-pick w = probas[y] ----------------
__device__ __forceinline__ float red256_sum(float v, float* red, int tid) {
  red[tid] = v; __syncthreads();
  #pragma unroll
  for (int st = 128; st > 0; st >>= 1) {
    if (tid < st) red[tid] += red[tid + st];
    __syncthreads();
  }
  float r = red[0]; __syncthreads();
  return r;
}
__device__ __forceinline__ float red256_max(float v, float* red, int tid) {
  red[tid] = v; __syncthreads();
  #pragma unroll
  for (int st = 128; st > 0; st >>= 1) {
    if (tid < st) red[tid] = fmaxf(red[tid], red[tid + st]);
    __syncthreads();
  }
  float r = red[0]; __syncthreads();
  return r;
}

__global__ __launch_bounds__(256) void pick_kernel(
    const float* __restrict__ preds, const int* __restrict__ y,
    float* __restrict__ w) {
  __shared__ float red[256];
  int row = blockIdx.x, tid = threadIdx.x;
  const float* pr = preds + (size_t)row * VOCAB_;
  float m = -INFINITY;
  for (int j = tid; j < VOCAB_; j += 256) m = fmaxf(m, pr[j]);
  float mx = red256_max(m, red, tid);
  float s = 0.f;
  for (int j = tid; j < VOCAB_; j += 256) s += expf(pr[j] - mx);
  float sum = red256_sum(s, red, tid);
  if (tid == 0) w[row] = expf(pr[y[row]] - mx) / sum;
}

// ---------------- w_norm + gumbel-max categorical -> i_t ----------------
__global__ __launch_bounds__(256) void cat_kernel(
    const float* __restrict__ w, int* __restrict__ i_t,
    uint32_t kc0, uint32_t kc1) {
  __shared__ float wv[256];
  __shared__ float wn[256];
  int tid = threadIdx.x;
  int b = tid >> 4;
  wv[tid] = w[tid];
  __syncthreads();
  float mx = -INFINITY;
  for (int j = 0; j < 16; j++) mx = fmaxf(mx, wv[b * 16 + j]);
  float ev = expf(wv[tid] - mx);
  wn[tid] = ev;
  __syncthreads();
  float sum = 0.f;
  for (int j = 0; j < 16; j++) sum += wn[b * 16 + j];
  __syncthreads();
  wn[tid] = ev / sum;
  __syncthreads();
  float best = -INFINITY;
  int bi = 0;
  for (int j = 0; j < 16; j++) {
    uint32_t idx = (uint32_t)tid * 16u + (uint32_t)j;
    float g = jax_gumbel(kc0, kc1, idx, 2048u);
    float sc = g + wn[b * 16 + j];
    if (sc > best) { best = sc; bi = j; }
  }
  i_t[tid] = bi;
}

// ---------------- resample/copy K,V,R — grid-stride, 16 float4/thread ------
// per tensor: 8,388,608 float4; 2048 blocks x 256 thr -> 16 iters/thread.
#define RS_BLOCKS 2048u
#define RS_STRIDE (RS_BLOCKS * 256u)   // 524288 threads per tensor
#define RS_ITERS  16

__global__ __launch_bounds__(256) void resample_kernel(
    const float4* __restrict__ Kin, const float4* __restrict__ Vin,
    const float4* __restrict__ Rin,
    const float4* __restrict__ knew, const float4* __restrict__ vnew,
    const float4* __restrict__ rnew,
    const int* __restrict__ i_t,
    float4* __restrict__ Kout, float4* __restrict__ Vout,
    float4* __restrict__ Rout) {
  const uint32_t base = blockIdx.x * 256u + threadIdx.x;
  const float4* in; const float4* nw; float4* out;
  if (blockIdx.y == 0)      { in = Kin; nw = knew; out = Kout; }
  else if (blockIdx.y == 1) { in = Vin; nw = vnew; out = Vout; }
  else                      { in = Rin; nw = rnew; out = Rout; }
  #pragma unroll 4
  for (int it = 0; it < RS_ITERS; it++) {
    uint32_t idx = base + (uint32_t)it * RS_STRIDE;
    uint32_t d4 = idx & 63u;
    uint32_t s  = (idx >> 6) & 511u;
    uint32_t p  = (idx >> 15) & 15u;
    uint32_t b  = idx >> 19;
    // branchless source select: one load per element
    const float4* src;
    if (s > T_) {
      src = in + idx;
    } else {
      uint32_t ip = (uint32_t)i_t[(b << 4) | p];
      src = (s == T_) ? (nw + ((((b << 4) | ip) << 6) | d4))
                      : (in + ((((((b << 4) | ip) << 9) | s) << 6) | d4));
    }
    out[idx] = *src;
  }
}

// ---------------- host ----------------
static void compute_subkeys(uint32_t nk[5][2]) {
  const uint32_t k0 = 0u, k1 = 1234u;
#if PARTITIONABLE
  for (uint32_t j = 0; j < 5; j++)
    threefry2x32_(k0, k1, 0u, j, nk[j][0], nk[j][1]);
#else
  uint32_t o0[5], o1[5], out[10];
  for (uint32_t m = 0; m < 5; m++) threefry2x32_(k0, k1, m, m + 5u, o0[m], o1[m]);
  for (int m = 0; m < 5; m++) { out[m] = o0[m]; out[m + 5] = o1[m]; }
  for (int j = 0; j < 5; j++) { nk[j][0] = out[2 * j]; nk[j][1] = out[2 * j + 1]; }
#endif
}

extern "C" void kernel_launch(void* const* d_in, const int* in_sizes, int n_in,
                              void* d_out, int out_size, void* d_ws, size_t ws_size,
                              hipStream_t stream) {
  const float* x    = (const float*)d_in[0];
  const int*   y    = (const int*)d_in[1];
  const float* Kin  = (const float*)d_in[2];
  const float* Vin  = (const float*)d_in[3];
  const float* Rin  = (const float*)d_in[4];
  const float* wq   = (const float*)d_in[5];  const float* bq = (const float*)d_in[6];
  const float* wk   = (const float*)d_in[7];  const float* bk = (const float*)d_in[8];
  const float* wv   = (const float*)d_in[9];  const float* bv = (const float*)d_in[10];
  const float* wo   = (const float*)d_in[11]; const float* bo = (const float*)d_in[12];
  const float* w1   = (const float*)d_in[13]; const float* b1 = (const float*)d_in[14];
  const float* w2   = (const float*)d_in[15]; const float* b2 = (const float*)d_in[16];
  const float* ln1g = (const float*)d_in[17]; const float* ln1b = (const float*)d_in[18];
  const float* ln2g = (const float*)d_in[19]; const float* ln2b = (const float*)d_in[20];
  const float* w_out = (const float*)d_in[21];
  const float* sigmas = (const float*)d_in[22];
  (void)in_sizes; (void)n_in; (void)out_size; (void)ws_size;

  // output layout (flat f32, return order): r, attn, noise_q, noise_z, K, V, R
  float* out        = (float*)d_out;
  float* r_out      = out;
  float* attn_out   = out + 65536;
  float* noiseq_out = out + 131328;
  float* noisez_out = out + 196864;
  float* K_out      = out + 262400;
  float* V_out      = out + 33816832;
  float* R_out      = out + 67371264;

  // workspace layout (floats)
  float* wsf   = (float*)d_ws;
  float* kws   = wsf;                  // 65536
  float* vws   = wsf + 65536;          // 65536
  float* preds = wsf + 131072;         // 1,280,000
  float* wprob = wsf + 1411072;        // 256
  int*   i_t   = (int*)(wsf + 1411328);

  uint32_t nk[5][2];
  compute_subkeys(nk);  // 0=q, 1=k, 2=v, 3=z, 4=categorical

  fused_row_kernel<<<ROWS_, 1024, 0, stream>>>(
      x, Kin, Vin, wq, bq, wk, bk, wv, bv, wo, bo, w1, b1, w2, b2,
      ln1g, ln1b, ln2g, ln2b, sigmas,
      kws, vws, attn_out, noiseq_out, noisez_out, r_out,
      nk[0][0], nk[0][1], nk[1][0], nk[1][1], nk[2][0], nk[2][1],
      nk[3][0], nk[3][1]);
  preds_kernel<<<dim3(20, 16), 256, 0, stream>>>(r_out, w_out, preds);
  pick_kernel<<<ROWS_, 256, 0, stream>>>(preds, y, wprob);
  cat_kernel<<<1, 256, 0, stream>>>(wprob, i_t, nk[4][0], nk[4][1]);
  resample_kernel<<<dim3(RS_BLOCKS, 3), 256, 0, stream>>>(
      (const float4*)Kin, (const float4*)Vin, (const float4*)Rin,
      (const float4*)kws, (const float4*)vws, (const float4*)r_out,
      i_t, (float4*)K_out, (float4*)V_out, (float4*)R_out);
}

// Round 4
// 284.467 us; speedup vs baseline: 1.0229x; 1.0229x over previous
//
#include <hip/hip_runtime.h>
#include <stdint.h>
#include <stddef.h>

// Problem constants (match reference setup_inputs)
#define B_    16
#define P_    16
#define S_    512
#define D_    256
#define DFF_  1024
#define VOCAB_ 5000
#define T_    256
#define ROWS_ 256        // B*P
#define EPS_  1e-6f

#define PARTITIONABLE 1  // jax_threefry_partitionable=True (verified in R1)

// ---------------- threefry2x32 (JAX reference cipher) ----------------
__host__ __device__ __forceinline__ uint32_t rotl32_(uint32_t x, int d) {
  return (x << d) | (x >> (32 - d));
}

__host__ __device__ __forceinline__ void threefry2x32_(uint32_t k0, uint32_t k1,
                                                       uint32_t x0, uint32_t x1,
                                                       uint32_t& o0, uint32_t& o1) {
  uint32_t ks2 = k0 ^ k1 ^ 0x1BD11BDAu;
  x0 += k0; x1 += k1;
  x0 += x1; x1 = rotl32_(x1, 13); x1 ^= x0;
  x0 += x1; x1 = rotl32_(x1, 15); x1 ^= x0;
  x0 += x1; x1 = rotl32_(x1, 26); x1 ^= x0;
  x0 += x1; x1 = rotl32_(x1,  6); x1 ^= x0;
  x0 += k1; x1 += ks2 + 1u;
  x0 += x1; x1 = rotl32_(x1, 17); x1 ^= x0;
  x0 += x1; x1 = rotl32_(x1, 29); x1 ^= x0;
  x0 += x1; x1 = rotl32_(x1, 16); x1 ^= x0;
  x0 += x1; x1 = rotl32_(x1, 24); x1 ^= x0;
  x0 += ks2; x1 += k0 + 2u;
  x0 += x1; x1 = rotl32_(x1, 13); x1 ^= x0;
  x0 += x1; x1 = rotl32_(x1, 15); x1 ^= x0;
  x0 += x1; x1 = rotl32_(x1, 26); x1 ^= x0;
  x0 += x1; x1 = rotl32_(x1,  6); x1 ^= x0;
  x0 += k0; x1 += k1 + 3u;
  x0 += x1; x1 = rotl32_(x1, 17); x1 ^= x0;
  x0 += x1; x1 = rotl32_(x1, 29); x1 ^= x0;
  x0 += x1; x1 = rotl32_(x1, 16); x1 ^= x0;
  x0 += x1; x1 = rotl32_(x1, 24); x1 ^= x0;
  x0 += k1; x1 += ks2 + 4u;
  x0 += x1; x1 = rotl32_(x1, 13); x1 ^= x0;
  x0 += x1; x1 = rotl32_(x1, 15); x1 ^= x0;
  x0 += x1; x1 = rotl32_(x1, 26); x1 ^= x0;
  x0 += x1; x1 = rotl32_(x1,  6); x1 ^= x0;
  x0 += ks2; x1 += k0 + 5u;
  o0 = x0; o1 = x1;
}

__device__ __forceinline__ uint32_t jax_bits(uint32_t k0, uint32_t k1,
                                             uint32_t i, uint32_t half) {
#if PARTITIONABLE
  uint32_t o0, o1;
  threefry2x32_(k0, k1, 0u, i, o0, o1);
  return o0 ^ o1;
#else
  uint32_t o0, o1;
  uint32_t lo = (i < half) ? i : (i - half);
  threefry2x32_(k0, k1, lo, lo + half, o0, o1);
  return (i < half) ? o0 : o1;
#endif
}

__device__ __forceinline__ float bits_to_u01(uint32_t b) {
  return __uint_as_float((b >> 9) | 0x3F800000u) - 1.0f;
}

// XLA f32 ErfInv (Giles polynomial)
__device__ __forceinline__ float erfinv32(float x) {
  float w = -log1pf(-x * x);
  float p;
  if (w < 5.0f) {
    w -= 2.5f;
    p = 2.81022636e-08f;
    p = fmaf(p, w, 3.43273939e-07f);
    p = fmaf(p, w, -3.5233877e-06f);
    p = fmaf(p, w, -4.39150654e-06f);
    p = fmaf(p, w, 0.00021858087f);
    p = fmaf(p, w, -0.00125372503f);
    p = fmaf(p, w, -0.00417768164f);
    p = fmaf(p, w, 0.246640727f);
    p = fmaf(p, w, 1.50140941f);
  } else {
    w = sqrtf(w) - 3.0f;
    p = -0.000200214257f;
    p = fmaf(p, w, 0.000100950558f);
    p = fmaf(p, w, 0.00134934322f);
    p = fmaf(p, w, -0.00367342844f);
    p = fmaf(p, w, 0.00573950773f);
    p = fmaf(p, w, -0.0076224613f);
    p = fmaf(p, w, 0.00943887047f);
    p = fmaf(p, w, 1.00167406f);
    p = fmaf(p, w, 2.83297682f);
  }
  return p * x;
}

__device__ __forceinline__ float jax_normal(uint32_t k0, uint32_t k1,
                                            uint32_t i, uint32_t half) {
  float u01 = bits_to_u01(jax_bits(k0, k1, i, half));
  const float lo = -0.99999994f;
  float u = __fadd_rn(__fmul_rn(u01, 2.0f), lo);
  u = fmaxf(lo, u);
  return 1.41421356f * erfinv32(u);
}

__device__ __forceinline__ float jax_gumbel(uint32_t k0, uint32_t k1,
                                            uint32_t i, uint32_t half) {
  float u01 = bits_to_u01(jax_bits(k0, k1, i, half));
  const float tiny = 1.17549435e-38f;
  float u = __fadd_rn(__fmul_rn(u01, 1.0f), tiny);
  u = fmaxf(tiny, u);
  return -logf(-logf(u));
}

// ---------------- 1024-thread block reductions (wave shfl + 16-slot LDS) ----
__device__ __forceinline__ float blk_sum(float v, float* red, int tid) {
  #pragma unroll
  for (int off = 32; off > 0; off >>= 1) v += __shfl_xor(v, off, 64);
  if ((tid & 63) == 0) red[tid >> 6] = v;
  __syncthreads();
  if (tid == 0) {
    float s = 0.f;
    #pragma unroll
    for (int i = 0; i < 16; i++) s += red[i];
    red[16] = s;
  }
  __syncthreads();
  float r = red[16];
  __syncthreads();
  return r;
}
__device__ __forceinline__ float blk_max(float v, float* red, int tid) {
  #pragma unroll
  for (int off = 32; off > 0; off >>= 1) v = fmaxf(v, __shfl_xor(v, off, 64));
  if ((tid & 63) == 0) red[tid >> 6] = v;
  __syncthreads();
  if (tid == 0) {
    float s = -INFINITY;
    #pragma unroll
    for (int i = 0; i < 16; i++) s = fmaxf(s, red[i]);
    red[16] = s;
  }
  __syncthreads();
  float r = red[16];
  __syncthreads();
  return r;
}

// ---------------- fused per-row kernel: qkv+noise+attn+wo+LN1+FFN+LN2 -------
// grid = 256 rows, block = 1024 threads (16 waves/CU for latency hiding)
__global__ __launch_bounds__(1024) void fused_row_kernel(
    const float* __restrict__ x,
    const float* __restrict__ Kin, const float* __restrict__ Vin,
    const float* __restrict__ wq, const float* __restrict__ bq,
    const float* __restrict__ wk, const float* __restrict__ bk,
    const float* __restrict__ wv, const float* __restrict__ bv,
    const float* __restrict__ wo, const float* __restrict__ bo,
    const float* __restrict__ w1, const float* __restrict__ b1,
    const float* __restrict__ w2, const float* __restrict__ b2,
    const float* __restrict__ ln1g, const float* __restrict__ ln1b,
    const float* __restrict__ ln2g, const float* __restrict__ ln2b,
    const float* __restrict__ sigmas,
    float* __restrict__ kws, float* __restrict__ vws,
    float* __restrict__ attn_out, float* __restrict__ noiseq_out,
    float* __restrict__ noisez_out, float* __restrict__ r_out,
    uint32_t kq0, uint32_t kq1, uint32_t kk0, uint32_t kk1,
    uint32_t kv0, uint32_t kv1, uint32_t kz0, uint32_t kz1) {
  __shared__ float xs[D_], qs[D_], ksh[D_], vsh[D_], z0s[D_], os[D_];
  __shared__ float att[T_ + 4];
  __shared__ float hs[DFF_];
  __shared__ float sc3[3][4][D_];   // split-K partials
  __shared__ float red[32];
  const int row = blockIdx.x, t = threadIdx.x;
  const int col = t & 255, ec = t >> 8;      // ec in [0,4)

  if (t < D_) xs[t] = x[row * D_ + t];
  __syncthreads();

  // ---- QKV: each quarter-thread-group accumulates a 64-long K-slice ----
  {
    float aq = 0.f, ak = 0.f, av = 0.f;
    const int e0 = ec * 64;
    #pragma unroll 8
    for (int e = e0; e < e0 + 64; e++) {
      float xe = xs[e];
      aq = fmaf(xe, wq[e * D_ + col], aq);
      ak = fmaf(xe, wk[e * D_ + col], ak);
      av = fmaf(xe, wv[e * D_ + col], av);
    }
    sc3[0][ec][col] = aq; sc3[1][ec][col] = ak; sc3[2][ec][col] = av;
  }
  __syncthreads();
  if (t < D_) {
    float qf = bq[t] + sc3[0][0][t] + sc3[0][1][t] + sc3[0][2][t] + sc3[0][3][t];
    float kf = bk[t] + sc3[1][0][t] + sc3[1][1][t] + sc3[1][2][t] + sc3[1][3][t];
    float vf = bv[t] + sc3[2][0][t] + sc3[2][1][t] + sc3[2][2][t] + sc3[2][3][t];
    uint32_t i = (uint32_t)row * D_ + t;
    float qn = qf + sigmas[0] * jax_normal(kq0, kq1, i, 32768u);
    float kn = kf + sigmas[1] * jax_normal(kk0, kk1, i, 32768u);
    float vn = vf + sigmas[2] * jax_normal(kv0, kv1, i, 32768u);
    qs[t] = qn; ksh[t] = kn; vsh[t] = vn;
    kws[i] = kn; vws[i] = vn;
    noiseq_out[i] = qn - qf;
  }
  __syncthreads();

  // ---- logits: 16 waves, 4 s-values per wave per round, float4 dot ----
  {
    const int wid = t >> 6, lane = t & 63;
    float4 myq = ((const float4*)qs)[lane];
    for (int s0 = wid * 4; s0 <= T_; s0 += 64) {
      #pragma unroll
      for (int j = 0; j < 4; j++) {
        int s = s0 + j;
        if (s <= T_) {
          const float* Krow = (s == T_) ? ksh
                                        : (Kin + ((size_t)row * S_ + s) * D_);
          float4 k4 = ((const float4*)Krow)[lane];
          float rr = myq.x * k4.x + myq.y * k4.y + myq.z * k4.z + myq.w * k4.w;
          #pragma unroll
          for (int off = 32; off > 0; off >>= 1) rr += __shfl_xor(rr, off, 64);
          if (lane == 0) att[s] = rr * 0.0625f;   // / sqrt(256)
        }
      }
    }
  }
  __syncthreads();

  // ---- softmax over 257 logits ----
  {
    float v = (t <= T_) ? att[t] : -INFINITY;
    float mx = blk_max(v, red, t);
    float e = (t <= T_) ? expf(att[t] - mx) : 0.f;
    float sum = blk_sum(e, red, t);
    if (t <= T_) {
      float a = e / sum;
      att[t] = a;
      attn_out[(size_t)row * (T_ + 1) + t] = a;
    }
  }
  __syncthreads();

  // ---- z0 = attn @ Vw (split s-range across ec) ----
  {
    float acc = 0.f;
    const int s0 = ec * 64;
    #pragma unroll 8
    for (int s = s0; s < s0 + 64; s++)
      acc = fmaf(att[s], Vin[((size_t)row * S_ + s) * D_ + col], acc);
    if (ec == 3) acc = fmaf(att[T_], vsh[col], acc);
    sc3[0][ec][col] = acc;
  }
  __syncthreads();
  if (t < D_) z0s[t] = sc3[0][0][t] + sc3[0][1][t] + sc3[0][2][t] + sc3[0][3][t];
  __syncthreads();

  // ---- z = z0 @ wo + bo + noise; y = z + x; LN1 ----
  {
    float acc = 0.f;
    const int e0 = ec * 64;
    #pragma unroll 8
    for (int e = e0; e < e0 + 64; e++)
      acc = fmaf(z0s[e], wo[e * D_ + col], acc);
    sc3[0][ec][col] = acc;
  }
  __syncthreads();
  if (t < D_) {
    float zp = bo[t] + sc3[0][0][t] + sc3[0][1][t] + sc3[0][2][t] + sc3[0][3][t];
    uint32_t i = (uint32_t)row * D_ + t;
    float zn = zp + sigmas[3] * jax_normal(kz0, kz1, i, 32768u);
    noisez_out[i] = zn - zp;
    z0s[t] = zn + xs[t];     // reuse z0s as y
  }
  __syncthreads();
  {
    float y = (t < D_) ? z0s[t] : 0.f;
    float mu = blk_sum(y, red, t) * (1.0f / 256.0f);
    float dv = (t < D_) ? (z0s[t] - mu) : 0.f;
    float var = blk_sum(dv * dv, red, t) * (1.0f / 256.0f);
    if (t < D_) os[t] = dv * rsqrtf(var + EPS_) * ln1g[t] + ln1b[t];
  }
  __syncthreads();

  // ---- FFN layer 1: all 1024 threads, one DFF output each ----
  {
    float acc = b1[t];
    #pragma unroll 8
    for (int e = 0; e < D_; e++) acc = fmaf(os[e], w1[(size_t)e * DFF_ + t], acc);
    hs[t] = fmaxf(acc, 0.f);
  }
  __syncthreads();

  // ---- FFN layer 2: split 1024-long K across ec ----
  {
    float acc = 0.f;
    const int e0 = ec * 256;
    #pragma unroll 8
    for (int e = e0; e < e0 + 256; e++)
      acc = fmaf(hs[e], w2[(size_t)e * D_ + col], acc);
    sc3[0][ec][col] = acc;
  }
  __syncthreads();
  if (t < D_) {
    float f = b2[t] + sc3[0][0][t] + sc3[0][1][t] + sc3[0][2][t] + sc3[0][3][t];
    z0s[t] = f + os[t];
  }
  __syncthreads();
  {
    float y = (t < D_) ? z0s[t] : 0.f;
    float mu = blk_sum(y, red, t) * (1.0f / 256.0f);
    float dv = (t < D_) ? (z0s[t] - mu) : 0.f;
    float var = blk_sum(dv * dv, red, t) * (1.0f / 256.0f);
    if (t < D_)
      r_out[(size_t)row * D_ + t] = dv * rsqrtf(var + EPS_) * ln2g[t] + ln2b[t];
  }
}

// ---------------- preds = r @ w_out (256x5000x256) ----------------
__global__ __launch_bounds__(256) void preds_kernel(
    const float* __restrict__ r, const float* __restrict__ w_out,
    float* __restrict__ preds) {
  int tid = threadIdx.x;
  int col = blockIdx.x * 250 + tid;
  int rb = blockIdx.y * 16;
  if (tid >= 250) return;
  float acc[16];
  #pragma unroll
  for (int m = 0; m < 16; m++) acc[m] = 0.f;
  #pragma unroll 4
  for (int e = 0; e < D_; e++) {
    float wv = w_out[(size_t)e * VOCAB_ + col];
    #pragma unroll
    for (int m = 0; m < 16; m++)
      acc[m] = fmaf(r[(size_t)(rb + m) * D_ + e], wv, acc[m]);
  }
  #pragma unroll
  for (int m = 0; m < 16; m++)
    preds[(size_t)(rb + m) * VOCAB_ + col] = acc[m];
}

// ---------------- softmax-pick w = probas[y] ----------------
__device__ __forceinline__ float red256_sum(float v, float* red, int tid) {
  red[tid] = v; __syncthreads();
  #pragma unroll
  for (int st = 128; st > 0; st >>= 1) {
    if (tid < st) red[tid] += red[tid + st];
    __syncthreads();
  }
  float r = red[0]; __syncthreads();
  return r;
}
__device__ __forceinline__ float red256_max(float v, float* red, int tid) {
  red[tid] = v; __syncthreads();
  #pragma unroll
  for (int st = 128; st > 0; st >>= 1) {
    if (tid < st) red[tid] = fmaxf(red[tid], red[tid + st]);
    __syncthreads();
  }
  float r = red[0]; __syncthreads();
  return r;
}

__global__ __launch_bounds__(256) void pick_kernel(
    const float* __restrict__ preds, const int* __restrict__ y,
    float* __restrict__ w) {
  __shared__ float red[256];
  int row = blockIdx.x, tid = threadIdx.x;
  const float* pr = preds + (size_t)row * VOCAB_;
  float m = -INFINITY;
  for (int j = tid; j < VOCAB_; j += 256) m = fmaxf(m, pr[j]);
  float mx = red256_max(m, red, tid);
  float s = 0.f;
  for (int j = tid; j < VOCAB_; j += 256) s += expf(pr[j] - mx);
  float sum = red256_sum(s, red, tid);
  if (tid == 0) w[row] = expf(pr[y[row]] - mx) / sum;
}

// ---------------- w_norm + gumbel-max categorical -> i_t ----------------
__global__ __launch_bounds__(256) void cat_kernel(
    const float* __restrict__ w, int* __restrict__ i_t,
    uint32_t kc0, uint32_t kc1) {
  __shared__ float wv[256];
  __shared__ float wn[256];
  int tid = threadIdx.x;
  int b = tid >> 4;
  wv[tid] = w[tid];
  __syncthreads();
  float mx = -INFINITY;
  for (int j = 0; j < 16; j++) mx = fmaxf(mx, wv[b * 16 + j]);
  float ev = expf(wv[tid] - mx);
  wn[tid] = ev;
  __syncthreads();
  float sum = 0.f;
  for (int j = 0; j < 16; j++) sum += wn[b * 16 + j];
  __syncthreads();
  wn[tid] = ev / sum;
  __syncthreads();
  float best = -INFINITY;
  int bi = 0;
  for (int j = 0; j < 16; j++) {
    uint32_t idx = (uint32_t)tid * 16u + (uint32_t)j;
    float g = jax_gumbel(kc0, kc1, idx, 2048u);
    float sc = g + wn[b * 16 + j];
    if (sc > best) { best = sc; bi = j; }
  }
  i_t[tid] = bi;
}

// ---------------- resample/copy K,V,R — bp-uniform blocks ----------------
// blockIdx.x = bp (0..255): i_t[bp] is a block-uniform SCALAR load, amortized
// over the block's 64 KB of traffic (fixes the per-thread dependent-load
// chain that throttled R2/R3 to ~3.6 TB/s).
// blockIdx.y = s-group (64 s-rows each, 8 groups), blockIdx.z = tensor.
// 1024 threads x 4 float4 (loads batched before stores -> MLP=4).
__global__ __launch_bounds__(1024) void resample_kernel(
    const float4* __restrict__ Kin, const float4* __restrict__ Vin,
    const float4* __restrict__ Rin,
    const float4* __restrict__ knew, const float4* __restrict__ vnew,
    const float4* __restrict__ rnew,
    const int* __restrict__ i_t,
    float4* __restrict__ Kout, float4* __restrict__ Vout,
    float4* __restrict__ Rout) {
  const uint32_t bp = blockIdx.x;        // particle row (b*16+p), uniform
  const uint32_t g  = blockIdx.y;        // s-group: rows [g*64, g*64+64)
  const uint32_t t  = threadIdx.x;
  const float4* in; const float4* nw; float4* out;
  if (blockIdx.z == 0)      { in = Kin; nw = knew; out = Kout; }
  else if (blockIdx.z == 1) { in = Vin; nw = vnew; out = Vout; }
  else                      { in = Rin; nw = rnew; out = Rout; }
  const uint32_t b = bp >> 4;
  const uint32_t ip = (uint32_t)i_t[bp];          // block-uniform -> s_load
  const uint32_t srcbp = (b << 4) | ip;
  const uint32_t d4 = t & 63u;
  const uint32_t rowoff = t >> 6;                 // 0..15

  float4 v[4];
  uint32_t dsts[4];
  #pragma unroll
  for (int j = 0; j < 4; j++) {
    uint32_t s = g * 64u + (uint32_t)j * 16u + rowoff;
    uint32_t dst = (bp << 15) | (s << 6) | d4;
    const float4* src;
    if (s < T_)       src = in + ((srcbp << 15) | (s << 6) | d4);
    else if (s == T_) src = nw + ((srcbp << 6) | d4);
    else              src = in + dst;
    v[j] = *src;
    dsts[j] = dst;
  }
  #pragma unroll
  for (int j = 0; j < 4; j++) out[dsts[j]] = v[j];
}

// ---------------- host ----------------
static void compute_subkeys(uint32_t nk[5][2]) {
  const uint32_t k0 = 0u, k1 = 1234u;
#if PARTITIONABLE
  for (uint32_t j = 0; j < 5; j++)
    threefry2x32_(k0, k1, 0u, j, nk[j][0], nk[j][1]);
#else
  uint32_t o0[5], o1[5], out[10];
  for (uint32_t m = 0; m < 5; m++) threefry2x32_(k0, k1, m, m + 5u, o0[m], o1[m]);
  for (int m = 0; m < 5; m++) { out[m] = o0[m]; out[m + 5] = o1[m]; }
  for (int j = 0; j < 5; j++) { nk[j][0] = out[2 * j]; nk[j][1] = out[2 * j + 1]; }
#endif
}

extern "C" void kernel_launch(void* const* d_in, const int* in_sizes, int n_in,
                              void* d_out, int out_size, void* d_ws, size_t ws_size,
                              hipStream_t stream) {
  const float* x    = (const float*)d_in[0];
  const int*   y    = (const int*)d_in[1];
  const float* Kin  = (const float*)d_in[2];
  const float* Vin  = (const float*)d_in[3];
  const float* Rin  = (const float*)d_in[4];
  const float* wq   = (const float*)d_in[5];  const float* bq = (const float*)d_in[6];
  const float* wk   = (const float*)d_in[7];  const float* bk = (const float*)d_in[8];
  const float* wv   = (const float*)d_in[9];  const float* bv = (const float*)d_in[10];
  const float* wo   = (const float*)d_in[11]; const float* bo = (const float*)d_in[12];
  const float* w1   = (const float*)d_in[13]; const float* b1 = (const float*)d_in[14];
  const float* w2   = (const float*)d_in[15]; const float* b2 = (const float*)d_in[16];
  const float* ln1g = (const float*)d_in[17]; const float* ln1b = (const float*)d_in[18];
  const float* ln2g = (const float*)d_in[19]; const float* ln2b = (const float*)d_in[20];
  const float* w_out = (const float*)d_in[21];
  const float* sigmas = (const float*)d_in[22];
  (void)in_sizes; (void)n_in; (void)out_size; (void)ws_size;

  // output layout (flat f32, return order): r, attn, noise_q, noise_z, K, V, R
  float* out        = (float*)d_out;
  float* r_out      = out;
  float* attn_out   = out + 65536;
  float* noiseq_out = out + 131328;
  float* noisez_out = out + 196864;
  float* K_out      = out + 262400;
  float* V_out      = out + 33816832;
  float* R_out      = out + 67371264;

  // workspace layout (floats)
  float* wsf   = (float*)d_ws;
  float* kws   = wsf;                  // 65536
  float* vws   = wsf + 65536;          // 65536
  float* preds = wsf + 131072;         // 1,280,000
  float* wprob = wsf + 1411072;        // 256
  int*   i_t   = (int*)(wsf + 1411328);

  uint32_t nk[5][2];
  compute_subkeys(nk);  // 0=q, 1=k, 2=v, 3=z, 4=categorical

  fused_row_kernel<<<ROWS_, 1024, 0, stream>>>(
      x, Kin, Vin, wq, bq, wk, bk, wv, bv, wo, bo, w1, b1, w2, b2,
      ln1g, ln1b, ln2g, ln2b, sigmas,
      kws, vws, attn_out, noiseq_out, noisez_out, r_out,
      nk[0][0], nk[0][1], nk[1][0], nk[1][1], nk[2][0], nk[2][1],
      nk[3][0], nk[3][1]);
  preds_kernel<<<dim3(20, 16), 256, 0, stream>>>(r_out, w_out, preds);
  pick_kernel<<<ROWS_, 256, 0, stream>>>(preds, y, wprob);
  cat_kernel<<<1, 256, 0, stream>>>(wprob, i_t, nk[4][0], nk[4][1]);
  resample_kernel<<<dim3(ROWS_, 8, 3), 1024, 0, stream>>>(
      (const float4*)Kin, (const float4*)Vin, (const float4*)Rin,
      (const float4*)kws, (const float4*)vws, (const float4*)r_out,
      i_t, (float4*)K_out, (float4*)V_out, (float4*)R_out);
}

// Round 5
// 266.626 us; speedup vs baseline: 1.0914x; 1.0669x over previous
//
#include <hip/hip_runtime.h>
#include <stdint.h>
#include <stddef.h>

// Problem constants (match reference setup_inputs)
#define B_    16
#define P_    16
#define S_    512
#define D_    256
#define DFF_  1024
#define VOCAB_ 5000
#define T_    256
#define ROWS_ 256        // B*P
#define EPS_  1e-6f

#define PARTITIONABLE 1  // jax_threefry_partitionable=True (verified in R1)

// ---------------- threefry2x32 (JAX reference cipher) ----------------
__host__ __device__ __forceinline__ uint32_t rotl32_(uint32_t x, int d) {
  return (x << d) | (x >> (32 - d));
}

__host__ __device__ __forceinline__ void threefry2x32_(uint32_t k0, uint32_t k1,
                                                       uint32_t x0, uint32_t x1,
                                                       uint32_t& o0, uint32_t& o1) {
  uint32_t ks2 = k0 ^ k1 ^ 0x1BD11BDAu;
  x0 += k0; x1 += k1;
  x0 += x1; x1 = rotl32_(x1, 13); x1 ^= x0;
  x0 += x1; x1 = rotl32_(x1, 15); x1 ^= x0;
  x0 += x1; x1 = rotl32_(x1, 26); x1 ^= x0;
  x0 += x1; x1 = rotl32_(x1,  6); x1 ^= x0;
  x0 += k1; x1 += ks2 + 1u;
  x0 += x1; x1 = rotl32_(x1, 17); x1 ^= x0;
  x0 += x1; x1 = rotl32_(x1, 29); x1 ^= x0;
  x0 += x1; x1 = rotl32_(x1, 16); x1 ^= x0;
  x0 += x1; x1 = rotl32_(x1, 24); x1 ^= x0;
  x0 += ks2; x1 += k0 + 2u;
  x0 += x1; x1 = rotl32_(x1, 13); x1 ^= x0;
  x0 += x1; x1 = rotl32_(x1, 15); x1 ^= x0;
  x0 += x1; x1 = rotl32_(x1, 26); x1 ^= x0;
  x0 += x1; x1 = rotl32_(x1,  6); x1 ^= x0;
  x0 += k0; x1 += k1 + 3u;
  x0 += x1; x1 = rotl32_(x1, 17); x1 ^= x0;
  x0 += x1; x1 = rotl32_(x1, 29); x1 ^= x0;
  x0 += x1; x1 = rotl32_(x1, 16); x1 ^= x0;
  x0 += x1; x1 = rotl32_(x1, 24); x1 ^= x0;
  x0 += k1; x1 += ks2 + 4u;
  x0 += x1; x1 = rotl32_(x1, 13); x1 ^= x0;
  x0 += x1; x1 = rotl32_(x1, 15); x1 ^= x0;
  x0 += x1; x1 = rotl32_(x1, 26); x1 ^= x0;
  x0 += x1; x1 = rotl32_(x1,  6); x1 ^= x0;
  x0 += ks2; x1 += k0 + 5u;
  o0 = x0; o1 = x1;
}

__device__ __forceinline__ uint32_t jax_bits(uint32_t k0, uint32_t k1,
                                             uint32_t i) {
#if PARTITIONABLE
  uint32_t o0, o1;
  threefry2x32_(k0, k1, 0u, i, o0, o1);
  return o0 ^ o1;
#else
  return 0u;  // legacy path unused (verified partitionable in R1)
#endif
}

__device__ __forceinline__ float bits_to_u01(uint32_t b) {
  return __uint_as_float((b >> 9) | 0x3F800000u) - 1.0f;
}

// XLA f32 ErfInv (Giles polynomial)
__device__ __forceinline__ float erfinv32(float x) {
  float w = -log1pf(-x * x);
  float p;
  if (w < 5.0f) {
    w -= 2.5f;
    p = 2.81022636e-08f;
    p = fmaf(p, w, 3.43273939e-07f);
    p = fmaf(p, w, -3.5233877e-06f);
    p = fmaf(p, w, -4.39150654e-06f);
    p = fmaf(p, w, 0.00021858087f);
    p = fmaf(p, w, -0.00125372503f);
    p = fmaf(p, w, -0.00417768164f);
    p = fmaf(p, w, 0.246640727f);
    p = fmaf(p, w, 1.50140941f);
  } else {
    w = sqrtf(w) - 3.0f;
    p = -0.000200214257f;
    p = fmaf(p, w, 0.000100950558f);
    p = fmaf(p, w, 0.00134934322f);
    p = fmaf(p, w, -0.00367342844f);
    p = fmaf(p, w, 0.00573950773f);
    p = fmaf(p, w, -0.0076224613f);
    p = fmaf(p, w, 0.00943887047f);
    p = fmaf(p, w, 1.00167406f);
    p = fmaf(p, w, 2.83297682f);
  }
  return p * x;
}

__device__ __forceinline__ float jax_normal(uint32_t k0, uint32_t k1,
                                            uint32_t i) {
  float u01 = bits_to_u01(jax_bits(k0, k1, i));
  const float lo = -0.99999994f;
  float u = __fadd_rn(__fmul_rn(u01, 2.0f), lo);
  u = fmaxf(lo, u);
  return 1.41421356f * erfinv32(u);
}

__device__ __forceinline__ float jax_gumbel(uint32_t k0, uint32_t k1,
                                            uint32_t i) {
  float u01 = bits_to_u01(jax_bits(k0, k1, i));
  const float tiny = 1.17549435e-38f;
  float u = __fadd_rn(__fmul_rn(u01, 1.0f), tiny);
  u = fmaxf(tiny, u);
  return -logf(-logf(u));
}

// ---------------- 1024-thread block reductions (wave shfl + 16-slot LDS) ----
__device__ __forceinline__ float blk_sum(float v, float* red, int tid) {
  #pragma unroll
  for (int off = 32; off > 0; off >>= 1) v += __shfl_xor(v, off, 64);
  if ((tid & 63) == 0) red[tid >> 6] = v;
  __syncthreads();
  if (tid == 0) {
    float s = 0.f;
    #pragma unroll
    for (int i = 0; i < 16; i++) s += red[i];
    red[16] = s;
  }
  __syncthreads();
  float r = red[16];
  __syncthreads();
  return r;
}
__device__ __forceinline__ float blk_max(float v, float* red, int tid) {
  #pragma unroll
  for (int off = 32; off > 0; off >>= 1) v = fmaxf(v, __shfl_xor(v, off, 64));
  if ((tid & 63) == 0) red[tid >> 6] = v;
  __syncthreads();
  if (tid == 0) {
    float s = -INFINITY;
    #pragma unroll
    for (int i = 0; i < 16; i++) s = fmaxf(s, red[i]);
    red[16] = s;
  }
  __syncthreads();
  float r = red[16];
  __syncthreads();
  return r;
}

// ---------------- fused per-row kernel (float4 dot phases) ------------------
// grid = 256 rows, block = 1024 threads.
// All weight dots use float4 loads (16B/lane = 1KB/wave/inst) with 16-way
// (or 4-way) split-K into LDS partials — ~4x fewer load issues than R2-R4.
__global__ __launch_bounds__(1024) void fused_row_kernel(
    const float* __restrict__ x,
    const float* __restrict__ Kin, const float* __restrict__ Vin,
    const float* __restrict__ wq, const float* __restrict__ bq,
    const float* __restrict__ wk, const float* __restrict__ bk,
    const float* __restrict__ wv, const float* __restrict__ bv,
    const float* __restrict__ wo, const float* __restrict__ bo,
    const float* __restrict__ w1, const float* __restrict__ b1,
    const float* __restrict__ w2, const float* __restrict__ b2,
    const float* __restrict__ ln1g, const float* __restrict__ ln1b,
    const float* __restrict__ ln2g, const float* __restrict__ ln2b,
    const float* __restrict__ sigmas,
    float* __restrict__ kws, float* __restrict__ vws,
    float* __restrict__ attn_out, float* __restrict__ noiseq_out,
    float* __restrict__ noisez_out, float* __restrict__ r_out,
    uint32_t kq0, uint32_t kq1, uint32_t kk0, uint32_t kk1,
    uint32_t kv0, uint32_t kv1, uint32_t kz0, uint32_t kz1) {
  __shared__ float xs[D_], qs[D_], ksh[D_], vsh[D_], z0s[D_], os[D_];
  __shared__ float att[T_ + 4];
  __shared__ float hs[DFF_];
  __shared__ float4 scq[16][64];   // 16KB  (also reused as [4][256] for FFN1)
  __shared__ float4 sck[16][64];   // 16KB
  __shared__ float4 scv[16][64];   // 16KB
  __shared__ float red[32];
  const int row = blockIdx.x, t = threadIdx.x;
  const int cg = t & 63;           // float4 col group (64 groups x 4 cols)
  const int sl = t >> 6;           // 0..15 K-slice

  if (t < D_) xs[t] = x[row * D_ + t];
  __syncthreads();

  // ---- QKV partials: slice sl covers e in [sl*16, sl*16+16), float4 cols --
  {
    const float4* wqf = (const float4*)wq;
    const float4* wkf = (const float4*)wk;
    const float4* wvf = (const float4*)wv;
    float4 aq = {0,0,0,0}, ak = {0,0,0,0}, av = {0,0,0,0};
    const int e0 = sl * 16;
    #pragma unroll
    for (int e = e0; e < e0 + 16; e++) {
      float xe = xs[e];
      float4 a = wqf[e * 64 + cg];
      float4 b = wkf[e * 64 + cg];
      float4 c = wvf[e * 64 + cg];
      aq.x = fmaf(xe, a.x, aq.x); aq.y = fmaf(xe, a.y, aq.y);
      aq.z = fmaf(xe, a.z, aq.z); aq.w = fmaf(xe, a.w, aq.w);
      ak.x = fmaf(xe, b.x, ak.x); ak.y = fmaf(xe, b.y, ak.y);
      ak.z = fmaf(xe, b.z, ak.z); ak.w = fmaf(xe, b.w, ak.w);
      av.x = fmaf(xe, c.x, av.x); av.y = fmaf(xe, c.y, av.y);
      av.z = fmaf(xe, c.z, av.z); av.w = fmaf(xe, c.w, av.w);
    }
    scq[sl][cg] = aq; sck[sl][cg] = ak; scv[sl][cg] = av;
  }
  __syncthreads();
  // ---- reduce + bias + noise: 3 groups of 256 threads (q,k,v parallel) ----
  if (t < 768) {
    const int m = t >> 8, c = t & 255;
    const float* sc = (m == 0) ? (const float*)scq
                    : (m == 1) ? (const float*)sck : (const float*)scv;
    float s = 0.f;
    #pragma unroll
    for (int j = 0; j < 16; j++) s += sc[j * 256 + c];
    float bias = ((m == 0) ? bq : (m == 1) ? bk : bv)[c];
    float base = bias + s;
    uint32_t i = (uint32_t)row * D_ + c;
    uint32_t a0 = (m == 0) ? kq0 : (m == 1) ? kk0 : kv0;
    uint32_t a1 = (m == 0) ? kq1 : (m == 1) ? kk1 : kv1;
    float val = base + sigmas[m] * jax_normal(a0, a1, i);
    if (m == 0)      { qs[c] = val; noiseq_out[i] = val - base; }
    else if (m == 1) { ksh[c] = val; kws[i] = val; }
    else             { vsh[c] = val; vws[i] = val; }
  }
  __syncthreads();

  // ---- logits: 16 waves, 4 s-values per wave per round, float4 dot ----
  {
    const int wid = t >> 6, lane = t & 63;
    float4 myq = ((const float4*)qs)[lane];
    for (int s0 = wid * 4; s0 <= T_; s0 += 64) {
      #pragma unroll
      for (int j = 0; j < 4; j++) {
        int s = s0 + j;
        if (s <= T_) {
          const float* Krow = (s == T_) ? ksh
                                        : (Kin + ((size_t)row * S_ + s) * D_);
          float4 k4 = ((const float4*)Krow)[lane];
          float rr = myq.x * k4.x + myq.y * k4.y + myq.z * k4.z + myq.w * k4.w;
          #pragma unroll
          for (int off = 32; off > 0; off >>= 1) rr += __shfl_xor(rr, off, 64);
          if (lane == 0) att[s] = rr * 0.0625f;   // / sqrt(256)
        }
      }
    }
  }
  __syncthreads();

  // ---- softmax over 257 logits ----
  {
    float v = (t <= T_) ? att[t] : -INFINITY;
    float mx = blk_max(v, red, t);
    float e = (t <= T_) ? expf(att[t] - mx) : 0.f;
    float sum = blk_sum(e, red, t);
    if (t <= T_) {
      float a = e / sum;
      att[t] = a;
      attn_out[(size_t)row * (T_ + 1) + t] = a;
    }
  }
  __syncthreads();

  // ---- z0 = attn @ Vw: slice sl covers s in [sl*16, sl*16+16) ----
  {
    const float4* Vf = (const float4*)(Vin + (size_t)row * S_ * D_);
    float4 acc = {0,0,0,0};
    const int s0 = sl * 16;
    #pragma unroll
    for (int s = s0; s < s0 + 16; s++) {
      float a = att[s];
      float4 v4 = Vf[s * 64 + cg];
      acc.x = fmaf(a, v4.x, acc.x); acc.y = fmaf(a, v4.y, acc.y);
      acc.z = fmaf(a, v4.z, acc.z); acc.w = fmaf(a, v4.w, acc.w);
    }
    scq[sl][cg] = acc;
  }
  __syncthreads();
  if (t < D_) {
    float s = 0.f;
    #pragma unroll
    for (int j = 0; j < 16; j++) s += ((const float*)scq)[j * 256 + t];
    z0s[t] = s + att[T_] * vsh[t];
  }
  __syncthreads();

  // ---- z = z0 @ wo + bo + noise; y = z + x; LN1 ----
  {
    const float4* wof = (const float4*)wo;
    float4 acc = {0,0,0,0};
    const int e0 = sl * 16;
    #pragma unroll
    for (int e = e0; e < e0 + 16; e++) {
      float ze = z0s[e];
      float4 w4 = wof[e * 64 + cg];
      acc.x = fmaf(ze, w4.x, acc.x); acc.y = fmaf(ze, w4.y, acc.y);
      acc.z = fmaf(ze, w4.z, acc.z); acc.w = fmaf(ze, w4.w, acc.w);
    }
    sck[sl][cg] = acc;
  }
  __syncthreads();
  if (t < D_) {
    float s = 0.f;
    #pragma unroll
    for (int j = 0; j < 16; j++) s += ((const float*)sck)[j * 256 + t];
    float zp = bo[t] + s;
    uint32_t i = (uint32_t)row * D_ + t;
    float zn = zp + sigmas[3] * jax_normal(kz0, kz1, i);
    noisez_out[i] = zn - zp;
    z0s[t] = zn + xs[t];     // reuse z0s as y
  }
  __syncthreads();
  {
    float y = (t < D_) ? z0s[t] : 0.f;
    float mu = blk_sum(y, red, t) * (1.0f / 256.0f);
    float dv = (t < D_) ? (z0s[t] - mu) : 0.f;
    float var = blk_sum(dv * dv, red, t) * (1.0f / 256.0f);
    if (t < D_) os[t] = dv * rsqrtf(var + EPS_) * ln1g[t] + ln1b[t];
  }
  __syncthreads();

  // ---- FFN1: 256 col-groups (f4) x 4 e-slices of 64 ----
  {
    const int cg8 = t & 255, es = t >> 8;
    const float4* w1f = (const float4*)w1;   // [256 rows][256 f4 groups]
    float4 acc = {0,0,0,0};
    const int e0 = es * 64;
    #pragma unroll 8
    for (int e = e0; e < e0 + 64; e++) {
      float oe = os[e];
      float4 w4 = w1f[e * 256 + cg8];
      acc.x = fmaf(oe, w4.x, acc.x); acc.y = fmaf(oe, w4.y, acc.y);
      acc.z = fmaf(oe, w4.z, acc.z); acc.w = fmaf(oe, w4.w, acc.w);
    }
    ((float4*)scq)[es * 256 + cg8] = acc;    // scq as [4][256] f4 (16KB)
  }
  __syncthreads();
  {
    float s = 0.f;
    #pragma unroll
    for (int j = 0; j < 4; j++) s += ((const float*)scq)[j * 1024 + t];
    hs[t] = fmaxf(b1[t] + s, 0.f);
  }
  __syncthreads();

  // ---- FFN2: 64 col-groups (f4) x 16 e-slices of 64 ----
  {
    const float4* w2f = (const float4*)w2;   // [1024 rows][64 f4 groups]
    float4 acc = {0,0,0,0};
    const int e0 = sl * 64;
    #pragma unroll 8
    for (int e = e0; e < e0 + 64; e++) {
      float he = hs[e];
      float4 w4 = w2f[e * 64 + cg];
      acc.x = fmaf(he, w4.x, acc.x); acc.y = fmaf(he, w4.y, acc.y);
      acc.z = fmaf(he, w4.z, acc.z); acc.w = fmaf(he, w4.w, acc.w);
    }
    scv[sl][cg] = acc;
  }
  __syncthreads();
  if (t < D_) {
    float s = 0.f;
    #pragma unroll
    for (int j = 0; j < 16; j++) s += ((const float*)scv)[j * 256 + t];
    z0s[t] = b2[t] + s + os[t];
  }
  __syncthreads();
  {
    float y = (t < D_) ? z0s[t] : 0.f;
    float mu = blk_sum(y, red, t) * (1.0f / 256.0f);
    float dv = (t < D_) ? (z0s[t] - mu) : 0.f;
    float var = blk_sum(dv * dv, red, t) * (1.0f / 256.0f);
    if (t < D_)
      r_out[(size_t)row * D_ + t] = dv * rsqrtf(var + EPS_) * ln2g[t] + ln2b[t];
  }
}

// ---------------- preds = r @ w_out (256x5000x256) ----------------
__global__ __launch_bounds__(256) void preds_kernel(
    const float* __restrict__ r, const float* __restrict__ w_out,
    float* __restrict__ preds) {
  int tid = threadIdx.x;
  int col = blockIdx.x * 250 + tid;
  int rb = blockIdx.y * 16;
  if (tid >= 250) return;
  float acc[16];
  #pragma unroll
  for (int m = 0; m < 16; m++) acc[m] = 0.f;
  #pragma unroll 4
  for (int e = 0; e < D_; e++) {
    float wv = w_out[(size_t)e * VOCAB_ + col];
    #pragma unroll
    for (int m = 0; m < 16; m++)
      acc[m] = fmaf(r[(size_t)(rb + m) * D_ + e], wv, acc[m]);
  }
  #pragma unroll
  for (int m = 0; m < 16; m++)
    preds[(size_t)(rb + m) * VOCAB_ + col] = acc[m];
}

// ---------------- softmax-pick w = probas[y] ----------------
__device__ __forceinline__ float red256_sum(float v, float* red, int tid) {
  red[tid] = v; __syncthreads();
  #pragma unroll
  for (int st = 128; st > 0; st >>= 1) {
    if (tid < st) red[tid] += red[tid + st];
    __syncthreads();
  }
  float r = red[0]; __syncthreads();
  return r;
}
__device__ __forceinline__ float red256_max(float v, float* red, int tid) {
  red[tid] = v; __syncthreads();
  #pragma unroll
  for (int st = 128; st > 0; st >>= 1) {
    if (tid < st) red[tid] = fmaxf(red[tid], red[tid + st]);
    __syncthreads();
  }
  float r = red[0]; __syncthreads();
  return r;
}

__global__ __launch_bounds__(256) void pick_kernel(
    const float* __restrict__ preds, const int* __restrict__ y,
    float* __restrict__ w) {
  __shared__ float red[256];
  int row = blockIdx.x, tid = threadIdx.x;
  const float* pr = preds + (size_t)row * VOCAB_;
  float m = -INFINITY;
  for (int j = tid; j < VOCAB_; j += 256) m = fmaxf(m, pr[j]);
  float mx = red256_max(m, red, tid);
  float s = 0.f;
  for (int j = tid; j < VOCAB_; j += 256) s += expf(pr[j] - mx);
  float sum = red256_sum(s, red, tid);
  if (tid == 0) w[row] = expf(pr[y[row]] - mx) / sum;
}

// ---------------- w_norm + gumbel-max categorical -> i_t ----------------
__global__ __launch_bounds__(256) void cat_kernel(
    const float* __restrict__ w, int* __restrict__ i_t,
    uint32_t kc0, uint32_t kc1) {
  __shared__ float wv[256];
  __shared__ float wn[256];
  int tid = threadIdx.x;
  int b = tid >> 4;
  wv[tid] = w[tid];
  __syncthreads();
  float mx = -INFINITY;
  for (int j = 0; j < 16; j++) mx = fmaxf(mx, wv[b * 16 + j]);
  float ev = expf(wv[tid] - mx);
  wn[tid] = ev;
  __syncthreads();
  float sum = 0.f;
  for (int j = 0; j < 16; j++) sum += wn[b * 16 + j];
  __syncthreads();
  wn[tid] = ev / sum;
  __syncthreads();
  float best = -INFINITY;
  int bi = 0;
  for (int j = 0; j < 16; j++) {
    uint32_t idx = (uint32_t)tid * 16u + (uint32_t)j;
    float g = jax_gumbel(kc0, kc1, idx);
    float sc = g + wn[b * 16 + j];
    if (sc > best) { best = sc; bi = j; }
  }
  i_t[tid] = bi;
}

// ---------------- resample/copy K,V,R (R2 flat form — best measured) -------
__global__ __launch_bounds__(256) void resample_kernel(
    const float4* __restrict__ Kin, const float4* __restrict__ Vin,
    const float4* __restrict__ Rin,
    const float4* __restrict__ knew, const float4* __restrict__ vnew,
    const float4* __restrict__ rnew,
    const int* __restrict__ i_t,
    float4* __restrict__ Kout, float4* __restrict__ Vout,
    float4* __restrict__ Rout) {
  uint32_t idx = blockIdx.x * 256u + threadIdx.x;
  uint32_t d4 = idx & 63u;
  uint32_t s  = (idx >> 6) & 511u;
  uint32_t p  = (idx >> 15) & 15u;
  uint32_t b  = idx >> 19;
  const float4* in; const float4* nw; float4* out;
  if (blockIdx.y == 0)      { in = Kin; nw = knew; out = Kout; }
  else if (blockIdx.y == 1) { in = Vin; nw = vnew; out = Vout; }
  else                      { in = Rin; nw = rnew; out = Rout; }
  float4 val;
  if (s > T_) {
    val = in[idx];
  } else {
    uint32_t ip = (uint32_t)i_t[(b << 4) | p];
    if (s == T_) val = nw[(((b << 4) | ip) << 6) | d4];
    else         val = in[(((((b << 4) | ip) << 9) | s) << 6) | d4];
  }
  out[idx] = val;
}

// ---------------- host ----------------
static void compute_subkeys(uint32_t nk[5][2]) {
  const uint32_t k0 = 0u, k1 = 1234u;
  for (uint32_t j = 0; j < 5; j++)
    threefry2x32_(k0, k1, 0u, j, nk[j][0], nk[j][1]);
}

extern "C" void kernel_launch(void* const* d_in, const int* in_sizes, int n_in,
                              void* d_out, int out_size, void* d_ws, size_t ws_size,
                              hipStream_t stream) {
  const float* x    = (const float*)d_in[0];
  const int*   y    = (const int*)d_in[1];
  const float* Kin  = (const float*)d_in[2];
  const float* Vin  = (const float*)d_in[3];
  const float* Rin  = (const float*)d_in[4];
  const float* wq   = (const float*)d_in[5];  const float* bq = (const float*)d_in[6];
  const float* wk   = (const float*)d_in[7];  const float* bk = (const float*)d_in[8];
  const float* wv   = (const float*)d_in[9];  const float* bv = (const float*)d_in[10];
  const float* wo   = (const float*)d_in[11]; const float* bo = (const float*)d_in[12];
  const float* w1   = (const float*)d_in[13]; const float* b1 = (const float*)d_in[14];
  const float* w2   = (const float*)d_in[15]; const float* b2 = (const float*)d_in[16];
  const float* ln1g = (const float*)d_in[17]; const float* ln1b = (const float*)d_in[18];
  const float* ln2g = (const float*)d_in[19]; const float* ln2b = (const float*)d_in[20];
  const float* w_out = (const float*)d_in[21];
  const float* sigmas = (const float*)d_in[22];
  (void)in_sizes; (void)n_in; (void)out_size; (void)ws_size;

  // output layout (flat f32, return order): r, attn, noise_q, noise_z, K, V, R
  float* out        = (float*)d_out;
  float* r_out      = out;
  float* attn_out   = out + 65536;
  float* noiseq_out = out + 131328;
  float* noisez_out = out + 196864;
  float* K_out      = out + 262400;
  float* V_out      = out + 33816832;
  float* R_out      = out + 67371264;

  // workspace layout (floats)
  float* wsf   = (float*)d_ws;
  float* kws   = wsf;                  // 65536
  float* vws   = wsf + 65536;          // 65536
  float* preds = wsf + 131072;         // 1,280,000
  float* wprob = wsf + 1411072;        // 256
  int*   i_t   = (int*)(wsf + 1411328);

  uint32_t nk[5][2];
  compute_subkeys(nk);  // 0=q, 1=k, 2=v, 3=z, 4=categorical

  fused_row_kernel<<<ROWS_, 1024, 0, stream>>>(
      x, Kin, Vin, wq, bq, wk, bk, wv, bv, wo, bo, w1, b1, w2, b2,
      ln1g, ln1b, ln2g, ln2b, sigmas,
      kws, vws, attn_out, noiseq_out, noisez_out, r_out,
      nk[0][0], nk[0][1], nk[1][0], nk[1][1], nk[2][0], nk[2][1],
      nk[3][0], nk[3][1]);
  preds_kernel<<<dim3(20, 16), 256, 0, stream>>>(r_out, w_out, preds);
  pick_kernel<<<ROWS_, 256, 0, stream>>>(preds, y, wprob);
  cat_kernel<<<1, 256, 0, stream>>>(wprob, i_t, nk[4][0], nk[4][1]);
  resample_kernel<<<dim3(32768, 3), 256, 0, stream>>>(
      (const float4*)Kin, (const float4*)Vin, (const float4*)Rin,
      (const float4*)kws, (const float4*)vws, (const float4*)r_out,
      i_t, (float4*)K_out, (float4*)V_out, (float4*)R_out);
}